// Round 13
// baseline (141.258 us; speedup 1.0000x reference)
//
#include <hip/hip_runtime.h>

// RG-LRU fused kernel set for MI355X (gfx950)
// B=4, T=4096, D=1024
// R13 = R12 + epilogue lane-remap: shuffle acc so lane (lg,lr) owns cols
//   {2lr, 2lr+1} (was {lr, lr+16}) -> xb reads become coalesced u32,
//   ag stores become uint2, br/bi/decay become float2. K-loop unchanged.

#define B_ 4
#define T_ 4096
#define D_ 1024
#define BT_ (B_ * T_)          // 16384
#define NC_ 64                 // chunks over T (chunk = 64 steps)

#define BMR 256                // M rows per block
#define BNC 128                // d cols per block
#define BKT 64                 // K per tile
#define NT_ (D_ / BKT)         // 16 K-tiles
#define BUFB 65536             // bytes per LDS buffer (A 32K + B 32K)

typedef float v4f __attribute__((ext_vector_type(4)));
typedef __bf16 v8bf __attribute__((ext_vector_type(8)));
typedef unsigned int u32;

__device__ inline unsigned short f2bf(float f) {
    unsigned int u = __float_as_uint(f);
    u += 0x7FFFu + ((u >> 16) & 1u);   // RNE
    return (unsigned short)(u >> 16);
}
__device__ inline ushort4 f2bf4(float4 v) {
    return make_ushort4(f2bf(v.x), f2bf(v.y), f2bf(v.z), f2bf(v.w));
}
__device__ inline u32 pack2(float p, float h) {
    _Float16 ph = (_Float16)p, hh = (_Float16)h;
    unsigned short pu, hu;
    __builtin_memcpy(&pu, &ph, 2);
    __builtin_memcpy(&hu, &hh, 2);
    return ((u32)hu << 16) | pu;
}
__device__ inline float unp_lo(u32 v) {
    unsigned short u = (unsigned short)(v & 0xffffu);
    _Float16 h; __builtin_memcpy(&h, &u, 2); return (float)h;
}
__device__ inline float unp_hi(u32 v) {
    unsigned short u = (unsigned short)(v >> 16);
    _Float16 h; __builtin_memcpy(&h, &u, 2); return (float)h;
}
__device__ inline float bf2f(unsigned short u) {
    return __uint_as_float((u32)u << 16);
}
__device__ inline void gload16(const void* g, void* l) {
    __builtin_amdgcn_global_load_lds(
        (const __attribute__((address_space(1))) u32*)g,
        (__attribute__((address_space(3))) u32*)l, 16, 0, 0);
}

// ---------------------------------------------------------------- prep
__global__ void prep_kernel(const float4* __restrict__ x4,
                            const float4* __restrict__ wr4,
                            const float4* __restrict__ wi4,
                            const float* __restrict__ lam,
                            ushort4* __restrict__ xb4,
                            ushort4* __restrict__ wrb4,
                            ushort4* __restrict__ wib4,
                            float* __restrict__ decay) {
    const int n = gridDim.x * blockDim.x;
    const int tid = blockIdx.x * blockDim.x + threadIdx.x;
    const int nx4 = (BT_ * D_) / 4;
    const int nw4 = (D_ * D_) / 4;
    for (int i = tid; i < nx4; i += n) xb4[i] = f2bf4(x4[i]);
    for (int i = tid; i < nw4; i += n) {
        wrb4[i] = f2bf4(wr4[i]);
        wib4[i] = f2bf4(wi4[i]);
    }
    for (int i = tid; i < D_; i += n) {
        float sp = log1pf(expf(lam[i]));
        decay[i] = 8.0f * sp;
    }
}

// ---------------------------------------------------------------- gemm + gates + prefix
__global__ __launch_bounds__(512, 2) void gemm_gates(
    const unsigned short* __restrict__ xb,
    const unsigned short* __restrict__ wrb,
    const unsigned short* __restrict__ wib,
    const float* __restrict__ br,
    const float* __restrict__ bi,
    const float* __restrict__ decay,
    u32* __restrict__ ag,
    float* __restrict__ Pg,
    float* __restrict__ Hg) {
    __shared__ __align__(16) char lds[2 * BUFB];   // 128 KB

    const int tid = threadIdx.x;
    const int lane = tid & 63;
    const int wave = tid >> 6;      // 0..7
    const int wr = wave >> 2;       // 0..1
    const int wc = wave & 3;        // 0..3
    const int lr = lane & 15;
    const int lg = lane >> 4;

    // XCD-aware swizzle (bijective 8x8x8), kept from R12 (neutral, free)
    const int bid = blockIdx.x;
    const int by = (bid >> 3) & 7;                 // col-tile 0..7
    const int bx = (bid & 7) * 8 + (bid >> 6);     // row-tile 0..63
    const int rowbase = bx * BMR;
    const int colbase = by * BNC;

    // staging map
    const int srow = tid >> 3;                    // 0..63 within quarter
    const int kslot = (tid & 7) ^ (srow & 7);     // pre-swizzled global slot

    const unsigned short* gAq[4];
#pragma unroll
    for (int q = 0; q < 4; ++q)
        gAq[q] = xb + (size_t)(rowbase + q * 64 + srow) * D_ + kslot * 8;
    const unsigned short* gBq[4];
    gBq[0] = wrb + (size_t)(colbase + srow) * D_ + kslot * 8;
    gBq[1] = wib + (size_t)(colbase + srow) * D_ + kslot * 8;
    gBq[2] = wrb + (size_t)(colbase + 64 + srow) * D_ + kslot * 8;
    gBq[3] = wib + (size_t)(colbase + 64 + srow) * D_ + kslot * 8;

#define STG_A(nb, q, kel) gload16(gAq[q] + (kel), lds + (nb) * BUFB + (q) * 8192 + wave * 1024)
#define STG_B(nb, q, kel) gload16(gBq[q] + (kel), lds + (nb) * BUFB + 32768 + (q) * 8192 + wave * 1024)

    const int bo = (wc & 1) * 32;       // within-strip col offset
    const int bstrip = wc >> 1;         // d-strip

    v4f ar[8][2], ai[8][2];
#pragma unroll
    for (int mi = 0; mi < 8; ++mi)
#pragma unroll
        for (int nf = 0; nf < 2; ++nf)
#pragma unroll
            for (int j = 0; j < 4; ++j) { ar[mi][nf][j] = 0.0f; ai[mi][nf][j] = 0.0f; }

    v8bf cbr[2], cbi[2];

    // ---- prologue
    STG_A(0, 0, 0); STG_A(0, 1, 0); STG_A(0, 2, 0); STG_A(0, 3, 0);
    STG_B(0, 0, 0); STG_B(0, 1, 0); STG_B(0, 2, 0); STG_B(0, 3, 0);
    __builtin_amdgcn_sched_barrier(0);
    asm volatile("s_waitcnt vmcnt(0)");
    __builtin_amdgcn_s_barrier();

#define PHASE(lb, KS, MH, WAITCODE, STAGECODE)                                  \
    do {                                                                        \
        if ((MH) == 0) {                                                        \
            _Pragma("unroll")                                                   \
            for (int nf = 0; nf < 2; ++nf) {                                    \
                const int brr = bstrip * 128 + bo + nf * 16 + lr;               \
                cbr[nf] = *(const v8bf*)((lb) + 32768 + brr * 128 +             \
                                         (((KS) * 4 + lg) ^ (brr & 7)) * 16);   \
                const int bri = brr + 64;                                       \
                cbi[nf] = *(const v8bf*)((lb) + 32768 + bri * 128 +             \
                                         (((KS) * 4 + lg) ^ (bri & 7)) * 16);   \
            }                                                                   \
        }                                                                       \
        v8bf af[4];                                                             \
        _Pragma("unroll")                                                       \
        for (int m4 = 0; m4 < 4; ++m4) {                                        \
            const int row = wr * 128 + ((MH) * 4 + m4) * 16 + lr;               \
            af[m4] = *(const v8bf*)((lb) + row * 128 +                          \
                                    (((KS) * 4 + lg) ^ (row & 7)) * 16);        \
        }                                                                       \
        __builtin_amdgcn_sched_barrier(0);                                      \
        WAITCODE;                                                               \
        __builtin_amdgcn_s_barrier();                                           \
        STAGECODE;                                                              \
        __builtin_amdgcn_s_setprio(1);                                          \
        _Pragma("unroll")                                                       \
        for (int m4 = 0; m4 < 4; ++m4)                                          \
            _Pragma("unroll")                                                   \
            for (int nf = 0; nf < 2; ++nf) {                                    \
                ar[(MH) * 4 + m4][nf] = __builtin_amdgcn_mfma_f32_16x16x32_bf16( \
                    af[m4], cbr[nf], ar[(MH) * 4 + m4][nf], 0, 0, 0);           \
                ai[(MH) * 4 + m4][nf] = __builtin_amdgcn_mfma_f32_16x16x32_bf16( \
                    af[m4], cbi[nf], ai[(MH) * 4 + m4][nf], 0, 0, 0);           \
            }                                                                   \
        __builtin_amdgcn_s_setprio(0);                                          \
        __builtin_amdgcn_sched_barrier(0);                                      \
    } while (0)

    for (int t = 0; t < NT_; ++t) {
        const int sw = t & 1;
        const int nb = sw ^ 1;
        const char* lb = lds + sw * BUFB;
        const int knext = (t + 1) * BKT;
        const bool more = (t + 1 < NT_);

        PHASE(lb, 0, 0,
              { asm volatile("s_waitcnt vmcnt(0)"); },
              if (more) {
                  STG_B(nb, 0, knext); STG_B(nb, 1, knext);
                  STG_B(nb, 2, knext); STG_B(nb, 3, knext);
              });
        PHASE(lb, 0, 1, {},
              if (more) { STG_A(nb, 0, knext); STG_A(nb, 2, knext); });
        PHASE(lb, 1, 0, {},
              if (more) { STG_A(nb, 1, knext); STG_A(nb, 3, knext); });
        PHASE(lb, 1, 1,
              {
                  if (more) { asm volatile("s_waitcnt vmcnt(2)"); }
                  else      { asm volatile("s_waitcnt vmcnt(0)"); }
              },
              );
    }
#undef PHASE
#undef STG_A
#undef STG_B

    // ---- epilogue: lane-remapped gates + in-register chunk prefix scan ----
    // Lane (lg,lr) now owns cols c_local = {2lr, 2lr+1} of the wave's 32-col
    // strip. Source of acc value for col c: lane lg*16 + (c&15), reg nf=c>>4.
    const int cb = colbase + wc * 32;           // wave col strip base
    const int c0 = 2 * lr;                      // local col, s=0
    const int src0 = (lane & 48) | (c0 & 15);
    const int src1 = (lane & 48) | ((c0 + 1) & 15);
    const int sel0 = c0 >> 4;                   // 0/1: which nf reg
    const int sel1 = (c0 + 1) >> 4;

    const float2 brv2 = *(const float2*)&br[cb + c0];
    const float2 biv2 = *(const float2*)&bi[cb + c0];
    const float2 dec2 = *(const float2*)&decay[cb + c0];
    const float brv[2] = {brv2.x, brv2.y};
    const float biv[2] = {biv2.x, biv2.y};
    const float dec[2] = {dec2.x, dec2.y};

#pragma unroll
    for (int half = 0; half < 2; ++half) {
        float Sp[2] = {1.0f, 1.0f}, Sh[2] = {0.0f, 0.0f};
#pragma unroll
        for (int m4 = 0; m4 < 4; ++m4) {
            const int mi = half * 4 + m4;
            float av[2][4], gv[2][4];
#pragma unroll
            for (int rr = 0; rr < 4; ++rr) {
                const int grow = rowbase + wr * 128 + mi * 16 + lg * 4 + rr;
                const u32 xw = *(const u32*)&xb[(size_t)grow * D_ + cb + c0];
                const float xv0 = bf2f((unsigned short)(xw & 0xffffu));
                const float xv1 = bf2f((unsigned short)(xw >> 16));
                // remap acc via shfl (4 per {ar,ai} pair per rr)
                const float ra0 = __shfl(ar[mi][0][rr], src0, 64);
                const float ra1 = __shfl(ar[mi][1][rr], src0, 64);
                const float rb0 = __shfl(ar[mi][0][rr], src1, 64);
                const float rb1 = __shfl(ar[mi][1][rr], src1, 64);
                const float ia0 = __shfl(ai[mi][0][rr], src0, 64);
                const float ia1 = __shfl(ai[mi][1][rr], src0, 64);
                const float ib0 = __shfl(ai[mi][0][rr], src1, 64);
                const float ib1 = __shfl(ai[mi][1][rr], src1, 64);
                const float zr0 = (sel0 ? ra1 : ra0) + brv[0];
                const float zr1 = (sel1 ? rb1 : rb0) + brv[1];
                const float zi0 = (sel0 ? ia1 : ia0) + biv[0];
                const float zi1 = (sel1 ? ib1 : ib0) + biv[1];
                const float rg0 = 1.0f / (1.0f + __expf(-zr0));
                const float rg1 = 1.0f / (1.0f + __expf(-zr1));
                const float ig0 = 1.0f / (1.0f + __expf(-zi0));
                const float ig1 = 1.0f / (1.0f + __expf(-zi1));
                av[0][rr] = __expf(-dec[0] * rg0);
                av[1][rr] = __expf(-dec[1] * rg1);
                const float sc0 = sqrtf(fmaxf(1.0f - av[0][rr] * av[0][rr], 0.0f));
                const float sc1 = sqrtf(fmaxf(1.0f - av[1][rr] * av[1][rr], 0.0f));
                gv[0][rr] = sc0 * (ig0 * xv0);
                gv[1][rr] = sc1 * (ig1 * xv1);
            }
            float wp[2], wh[2];
#pragma unroll
            for (int s = 0; s < 2; ++s) {
                // lane-local compose over 4 rows
                float lp = (av[s][0] * av[s][1]) * (av[s][2] * av[s][3]);
                float lh = gv[s][0];
                lh = av[s][1] * lh + gv[s][1];
                lh = av[s][2] * lh + gv[s][2];
                lh = av[s][3] * lh + gv[s][3];
                // ordered inclusive scan across lg
                float cp = lp, ch = lh;
                {
                    const float pp = __shfl_up(cp, 16, 64);
                    const float ph = __shfl_up(ch, 16, 64);
                    if (lg >= 1) { ch = cp * ph + ch; cp = pp * cp; }
                }
                {
                    const float pp = __shfl_up(cp, 32, 64);
                    const float ph = __shfl_up(ch, 32, 64);
                    if (lg >= 2) { ch = cp * ph + ch; cp = pp * cp; }
                }
                // exclusive across lg
                float ep = __shfl_up(cp, 16, 64);
                float eh = __shfl_up(ch, 16, 64);
                if (lg == 0) { ep = 1.0f; eh = 0.0f; }
                wp[s] = Sp[s] * ep;
                wh[s] = ep * Sh[s] + eh;
                // advance S by full 16-row block (inclusive at lg==3, same lr)
                const float fp3 = __shfl(cp, 48 + lr, 64);
                const float fh3 = __shfl(ch, 48 + lr, 64);
                Sh[s] = fp3 * Sh[s] + fh3;
                Sp[s] = Sp[s] * fp3;
            }
#pragma unroll
            for (int rr = 0; rr < 4; ++rr) {
                const int grow = rowbase + wr * 128 + mi * 16 + lg * 4 + rr;
                uint2 pk;
                wh[0] = av[0][rr] * wh[0] + gv[0][rr];
                wp[0] = wp[0] * av[0][rr];
                wh[1] = av[1][rr] * wh[1] + gv[1][rr];
                wp[1] = wp[1] * av[1][rr];
                pk.x = pack2(wp[0], wh[0]);
                pk.y = pack2(wp[1], wh[1]);
                *(uint2*)&ag[(size_t)grow * D_ + cb + c0] = pk;
            }
        }
        if (lg == 0) {
            const int gc = (rowbase >> 6) + wr * 2 + half;   // global chunk id
            *(float2*)&Pg[(size_t)gc * D_ + cb + c0] = make_float2(Sp[0], Sp[1]);
            *(float2*)&Hg[(size_t)gc * D_ + cb + c0] = make_float2(Sh[0], Sh[1]);
        }
    }
}

// ---------------------------------------------------------------- combine
__global__ __launch_bounds__(256) void combine(const float* __restrict__ P,
                                               const float* __restrict__ H,
                                               const float* __restrict__ h0,
                                               float* __restrict__ hstart,
                                               float* __restrict__ hT) {
    const int idx = blockIdx.x * 256 + threadIdx.x;   // [0, B*D)
    const int d = idx & (D_ - 1);
    const int b = idx >> 10;
    float h = h0[b * D_ + d];
    for (int c = 0; c < NC_; ++c) {
        const int o = (b * NC_ + c) * D_ + d;
        hstart[o] = h;
        h = P[o] * h + H[o];
    }
    hT[b * D_ + d] = h;
}

// ---------------------------------------------------------------- scan2: pointwise fixup
__global__ __launch_bounds__(256) void scan2(const uint4* __restrict__ ag4,
                                             const float4* __restrict__ hs4,
                                             float4* __restrict__ out4) {
    const int n = (BT_ * D_) / 4;
    const int stride = gridDim.x * 256;
    for (int i = blockIdx.x * 256 + threadIdx.x; i < n; i += stride) {
        const int d4 = i & (D_ / 4 - 1);     // 0..255
        const int row = i >> 8;               // b*T + t
        const int b = row >> 12;
        const int c = (row & (T_ - 1)) >> 6;
        const float4 hs = hs4[(size_t)(b * NC_ + c) * (D_ / 4) + d4];
        const uint4 v = ag4[i];
        float4 o;
        o.x = unp_hi(v.x) + unp_lo(v.x) * hs.x;
        o.y = unp_hi(v.y) + unp_lo(v.y) * hs.y;
        o.z = unp_hi(v.z) + unp_lo(v.z) * hs.z;
        o.w = unp_hi(v.w) + unp_lo(v.w) * hs.w;
        out4[i] = o;
    }
}

// ---------------------------------------------------------------- launch
extern "C" void kernel_launch(void* const* d_in, const int* in_sizes, int n_in,
                              void* d_out, int out_size, void* d_ws, size_t ws_size,
                              hipStream_t stream) {
    const float* x   = (const float*)d_in[0];
    const float* h0  = (const float*)d_in[1];
    const float* Wr  = (const float*)d_in[2];
    const float* br  = (const float*)d_in[3];
    const float* Wi  = (const float*)d_in[4];
    const float* bi  = (const float*)d_in[5];
    const float* lam = (const float*)d_in[6];
    float* out = (float*)d_out;

    char* ws = (char*)d_ws;
    unsigned short* xb  = (unsigned short*)ws; ws += (size_t)BT_ * D_ * 2;   // 33.5 MB
    unsigned short* wrb = (unsigned short*)ws; ws += (size_t)D_ * D_ * 2;    //  2 MB
    unsigned short* wib = (unsigned short*)ws; ws += (size_t)D_ * D_ * 2;    //  2 MB
    float* decay  = (float*)ws;  ws += (size_t)D_ * 4;                       //  4 KB
    u32* ag       = (u32*)ws;    ws += (size_t)BT_ * D_ * 4;                 // 67 MB
    float* Pg     = (float*)ws;  ws += (size_t)B_ * NC_ * D_ * 4;            //  1 MB
    float* Hg     = (float*)ws;  ws += (size_t)B_ * NC_ * D_ * 4;            //  1 MB
    float* hstart = (float*)ws;                                              //  1 MB

    prep_kernel<<<2048, 256, 0, stream>>>(
        (const float4*)x, (const float4*)Wr, (const float4*)Wi, lam,
        (ushort4*)xb, (ushort4*)wrb, (ushort4*)wib, decay);

    gemm_gates<<<512, 512, 0, stream>>>(
        xb, wrb, wib, br, bi, decay, ag, Pg, Hg);

    combine<<<(B_ * D_) / 256, 256, 0, stream>>>(Pg, Hg, h0, hstart, out + (size_t)BT_ * D_);

    scan2<<<2048, 256, 0, stream>>>((const uint4*)ag, (const float4*)hstart, (float4*)out);
}